// Round 9
// baseline (5211.411 us; speedup 1.0000x reference)
//
#include <hip/hip_runtime.h>
#include <stdint.h>

typedef unsigned short ushort_t;
typedef __bf16 bf16x8 __attribute__((ext_vector_type(8)));
typedef float f32x4 __attribute__((ext_vector_type(4)));

// ---------- bf16 <-> f32 (bit ops) ----------
__device__ __forceinline__ float b2f(ushort_t u) {
  union { unsigned u; float f; } v; v.u = ((unsigned)u) << 16; return v.f;
}
__device__ __forceinline__ ushort_t f2b(float f) {
  union { float f; unsigned u; } v; v.f = f;
  unsigned r = (v.u + 0x7FFFu + ((v.u >> 16) & 1u)) >> 16;
  return (ushort_t)r;
}

// ---------- fast transcendentals (HW v_exp_f32 based) ----------
__device__ __forceinline__ float sigm(float x)     { return 1.f / (1.f + __expf(-x)); }
__device__ __forceinline__ float tanhfast(float x) { return 1.f - 2.f / (1.f + __expf(2.f * x)); }

// ---------- device-coherent write-through stores (visible at MALL) ----------
__device__ __forceinline__ void store_short_wt(ushort_t* p, ushort_t v) {
  asm volatile("global_store_short %0, %1, off sc0 sc1"
               :: "v"(p), "v"((unsigned)v) : "memory");
}
__device__ __forceinline__ void store_uint_wt(unsigned* p, unsigned v) {
  asm volatile("global_store_dword %0, %1, off sc0 sc1"
               :: "v"(p), "v"(v) : "memory");
}

// ---------- global -> LDS direct load, 16B per lane ----------
__device__ __forceinline__ void gload_lds16(const void* g, void* lds) {
  auto l3 = reinterpret_cast<__attribute__((address_space(3))) unsigned*>(
      reinterpret_cast<uintptr_t>(lds));
  __builtin_amdgcn_global_load_lds(reinterpret_cast<const unsigned*>(g), l3, 16, 0, 0);
}

// =====================================================================
// GEMM: C[M,N] = A[M,K] @ B[N,K]^T + bias0 + bias1 (bf16 in, f32 acc,
// bf16 or f32 out). BM=BN=128, BK=32, 256 thr (4 waves), global_load_lds
// staging + bijective XCD swizzle when nwg%8==0.
// =====================================================================
template <bool F32OUT>
__global__ __launch_bounds__(256) void gemm_bt(
    const ushort_t* __restrict__ A, const ushort_t* __restrict__ B,
    void* __restrict__ Cv,
    const float* __restrict__ bias0, const float* __restrict__ bias1,
    int lda, int ldb, int ldc, int Kpad, int N)
{
  __shared__ alignas(16) ushort_t As[128 * 32];
  __shared__ alignas(16) ushort_t Bs[128 * 32];
  const int tid = threadIdx.x;
  const int w = tid >> 6, l = tid & 63;
  const int wr = w >> 1, wc = w & 1;

  unsigned nwg = gridDim.x * gridDim.y;
  unsigned wg = blockIdx.y * gridDim.x + blockIdx.x;
  if ((nwg & 7u) == 0u) {
    unsigned cpx = nwg >> 3;
    wg = (wg & 7u) * cpx + (wg >> 3);
  }
  const long m0 = (long)(wg % gridDim.x) * 128;
  const long n0 = (long)(wg / gridDim.x) * 128;

  const int lrow = l & 15, lk = (l >> 4) * 8;

  f32x4 acc[4][4] = {};

  const int c0 = tid, c1 = tid + 256;
  const int r0 = c0 >> 2, g0 = (c0 & 3) * 8;
  const int r1 = c1 >> 2, g1 = (c1 & 3) * 8;

  for (int k0 = 0; k0 < Kpad; k0 += 32) {
    gload_lds16(A + (m0 + r0) * lda + k0 + g0, As + c0 * 8);
    gload_lds16(A + (m0 + r1) * lda + k0 + g1, As + c1 * 8);
    gload_lds16(B + (n0 + r0) * ldb + k0 + g0, Bs + c0 * 8);
    gload_lds16(B + (n0 + r1) * ldb + k0 + g1, Bs + c1 * 8);
    __syncthreads();

    bf16x8 af[4], bfr[4];
#pragma unroll
    for (int mi = 0; mi < 4; mi++)
      af[mi] = *(const bf16x8*)(As + (wr * 64 + mi * 16 + lrow) * 32 + lk);
#pragma unroll
    for (int ni = 0; ni < 4; ni++)
      bfr[ni] = *(const bf16x8*)(Bs + (wc * 64 + ni * 16 + lrow) * 32 + lk);
#pragma unroll
    for (int mi = 0; mi < 4; mi++)
#pragma unroll
      for (int ni = 0; ni < 4; ni++)
        acc[mi][ni] = __builtin_amdgcn_mfma_f32_16x16x32_bf16(af[mi], bfr[ni], acc[mi][ni], 0, 0, 0);
    __syncthreads();
  }

  const int rbase = (l >> 4) * 4;
#pragma unroll
  for (int ni = 0; ni < 4; ni++) {
    int gcol = (int)n0 + wc * 64 + ni * 16 + lrow;
    if (gcol < N) {
      float badd = 0.f;
      if (bias0) badd += bias0[gcol];
      if (bias1) badd += bias1[gcol];
#pragma unroll
      for (int mi = 0; mi < 4; mi++) {
#pragma unroll
        for (int r = 0; r < 4; r++) {
          long grow = m0 + wr * 64 + mi * 16 + rbase + r;
          float v = acc[mi][ni][r] + badd;
          if (F32OUT) ((float*)Cv)[grow * ldc + gcol] = v;
          else        ((ushort_t*)Cv)[grow * ldc + gcol] = f2b(v);
        }
      }
    }
  }
}

// =====================================================================
// Persistent LSTM layer, BARRIER-FREE: per-block monotonic flags.
// 72 blocks (16-unit slices) x 256 thr (4 waves = 4 batch-16 tiles).
// Block us publishes flag[us]=t+1 after draining its write-through h[t+1]
// stores. Consumers scan the 72 flags wave-parallel and consume h[t] in
// 36 K-chunks IN ORDER, each chunk gated only on its 2 producers -> poll
// latency overlaps the MFMA/load pipeline of earlier chunks.
// Whh slice staged once in 144KB LDS (chunk-XOR swizzle); cell in regs.
// =====================================================================
__global__ __launch_bounds__(256) void lstm_layer(
    ushort_t* __restrict__ hs,        // [101][64][1152] bf16
    const ushort_t* __restrict__ G,   // [6400][4608] bf16 (x@Wih^T + biases)
    const ushort_t* __restrict__ Whh, // padded [4608][1152] bf16
    const float* __restrict__ c_in,   // [64][1150] f32 initial cell
    unsigned* __restrict__ flags)     // 72 lines of 128B, zeroed per layer
{
  extern __shared__ ushort_t Bsh[];   // 4*16*144 chunks of 16B = 147456 B
  const int tid = threadIdx.x;
  const int w = tid >> 6, l = tid & 63;
  const int us = blockIdx.x;              // unit slice [0,72)
  const int lrow = l & 15, hi = l >> 4, lk = hi * 8;
  const int u = us * 16 + lrow;
  const int usafe = (u < 1150) ? u : 0;
  const int row0 = w * 16 + hi * 4;       // first batch row of this lane's D regs
  const int x7 = lrow & 7;

  // ---- stage Whh slice into LDS (once), chunk-swizzled: phys = c ^ (row&7) ----
  for (int ci = tid; ci < 9216; ci += 256) {
    int gate = ci / 2304;
    int rem  = ci - gate * 2304;
    int row  = rem / 144;
    int c    = rem - row * 144;
    bf16x8 v = *(const bf16x8*)(Whh + ((long)(gate * 1150 + us * 16 + row)) * 1152 + c * 8);
    *(bf16x8*)(Bsh + (((gate * 16 + row) * 144) + (c ^ (row & 7))) * 8) = v;
  }
  const ushort_t* Bg0 = Bsh + ((0 * 16 + lrow) * 144) * 8;
  const ushort_t* Bg1 = Bsh + ((1 * 16 + lrow) * 144) * 8;
  const ushort_t* Bg2 = Bsh + ((2 * 16 + lrow) * 144) * 8;
  const ushort_t* Bg3 = Bsh + ((3 * 16 + lrow) * 144) * 8;

  // ---- cell state in registers (lane owns rows row0..row0+3, col u) ----
  f32x4 cc = {};
  if (u < 1150) {
#pragma unroll
    for (int r = 0; r < 4; ++r) cc[r] = c_in[(row0 + r) * 1150 + u];
  }
  __syncthreads();   // LDS staging visible

  for (int t = 0; t < 100; ++t) {
    const unsigned target = (unsigned)t;   // need flag[s] >= t to read h[t]
    int avail = (t == 0) ? 72 : 0;         // h[0] written by init_state (pre-kernel)

    // wave-parallel availability scan: advances 'avail' = length of the
    // satisfied slice-prefix. Exits only when avail >= need.
    auto scan_until = [&](int need) {
      while (avail < need) {
        unsigned v1 = __hip_atomic_load(flags + (l << 5),
                                        __ATOMIC_RELAXED, __HIP_MEMORY_SCOPE_AGENT);
        unsigned v2 = __hip_atomic_load(flags + ((64 + (l & 7)) << 5),
                                        __ATOMIC_RELAXED, __HIP_MEMORY_SCOPE_AGENT);
        unsigned long long m1 = __ballot(v1 >= target);
        unsigned long long m2 = __ballot(v2 >= target);
        int p;
        if (m1 != ~0ull) {
          p = (int)__builtin_ctzll(~m1);
        } else {
          unsigned miss = (~(unsigned)m2) & 0xFFu;
          p = 64 + (miss ? (int)__builtin_ctz(miss) : 8);
        }
        if (p <= avail) __builtin_amdgcn_s_sleep(1);
        avail = p;
      }
      asm volatile("" ::: "memory");  // no load hoisting above the flag check
    };

    if (t != 0) scan_until(2);   // producers of chunk kc=0

    // G prefetch for this step (independent of h; completes under the MFMAs)
    ushort_t gvv[16];
    {
      const ushort_t* gp = G + ((long)t * 64 + row0) * 4608 + usafe;
#pragma unroll
      for (int r = 0; r < 4; ++r)
#pragma unroll
        for (int g = 0; g < 4; ++g)
          gvv[r * 4 + g] = gp[(long)r * 4608 + g * 1150];
    }

    const ushort_t* hp = hs + (long)t * 73728 + (long)(w * 16 + lrow) * 1152 + lk;
    f32x4 a0 = {}, a1 = {}, a2 = {}, a3 = {};
#pragma unroll 4
    for (int kc = 0; kc < 36; ++kc) {
      if (avail < 2 * kc + 2) scan_until(2 * kc + 2);
      bf16x8 a = *(const bf16x8*)(hp + kc * 32);
      int pc8 = ((kc * 4 + hi) ^ x7) * 8;
      a0 = __builtin_amdgcn_mfma_f32_16x16x32_bf16(a, *(const bf16x8*)(Bg0 + pc8), a0, 0, 0, 0);
      a1 = __builtin_amdgcn_mfma_f32_16x16x32_bf16(a, *(const bf16x8*)(Bg1 + pc8), a1, 0, 0, 0);
      a2 = __builtin_amdgcn_mfma_f32_16x16x32_bf16(a, *(const bf16x8*)(Bg2 + pc8), a2, 0, 0, 0);
      a3 = __builtin_amdgcn_mfma_f32_16x16x32_bf16(a, *(const bf16x8*)(Bg3 + pc8), a3, 0, 0, 0);
    }

    if (u < 1150) {
#pragma unroll
      for (int r = 0; r < 4; ++r) {
        float iv = a0[r] + b2f(gvv[r * 4 + 0]);
        float fv = a1[r] + b2f(gvv[r * 4 + 1]);
        float gg = a2[r] + b2f(gvv[r * 4 + 2]);
        float ov = a3[r] + b2f(gvv[r * 4 + 3]);
        float cn = sigm(fv) * cc[r] + sigm(iv) * tanhfast(gg);
        cc[r] = cn;
        float hv = sigm(ov) * tanhfast(cn);
        store_short_wt(hs + (long)(t + 1) * 73728 + (long)(row0 + r) * 1152 + u, f2b(hv));
      }
    }

    // publish: my h[t+1] slice is at the coherence point
    asm volatile("s_waitcnt vmcnt(0)" ::: "memory");  // per-wave store drain
    __syncthreads();                                  // all 4 waves drained
    if (tid == 0) store_uint_wt(flags + ((long)us << 5), (unsigned)(t + 1));
  }
}

// =====================================================================
// Fused causal attention for one (t,b): scores -> softmax -> PV. f32 math.
// =====================================================================
__global__ __launch_bounds__(256) void attn_kernel(
    const ushort_t* __restrict__ hs2,  // base at hs[1]: [100][64][1152] bf16
    ushort_t* __restrict__ outp)       // [6400][1152] bf16
{
  __shared__ float qf[1152];
  __shared__ float sc[104];
  __shared__ float sinv;
  const int rowi = blockIdx.x;  // t*64 + b
  const int t = rowi >> 6, b = rowi & 63;
  const int tid = threadIdx.x;
  const int w = tid >> 6, l = tid & 63;

  const ushort_t* q = hs2 + (long)rowi * 1152;
  for (int c = tid; c < 1150; c += 256) qf[c] = b2f(q[c]);
  __syncthreads();

  for (int s = w; s <= t; s += 4) {
    const ushort_t* k = hs2 + (long)(s * 64 + b) * 1152;
    float p = 0.f;
    for (int h = l; h < 1150; h += 64) p += qf[h] * b2f(k[h]);
    for (int off = 32; off; off >>= 1) p += __shfl_down(p, off);
    if (l == 0) sc[s] = p;
  }
  __syncthreads();

  if (w == 0) {
    float m = -1e30f;
    for (int s = l; s <= t; s += 64) m = fmaxf(m, sc[s]);
    for (int off = 32; off; off >>= 1) m = fmaxf(m, __shfl_down(m, off));
    m = __shfl(m, 0);
    float sum = 0.f;
    for (int s = l; s <= t; s += 64) { float e = __expf(sc[s] - m); sc[s] = e; sum += e; }
    for (int off = 32; off; off >>= 1) sum += __shfl_down(sum, off);
    if (l == 0) sinv = 1.f / sum;
  }
  __syncthreads();

  const float si = sinv;
  for (int h = tid; h < 1150; h += 256) {
    float a = 0.f;
    for (int s = 0; s <= t; s++) a += sc[s] * b2f(hs2[(long)(s * 64 + b) * 1152 + h]);
    outp[(long)rowi * 1152 + h] = f2b(a * si);
  }
  if (tid < 2) outp[(long)rowi * 1152 + 1150 + tid] = 0;  // zero K-pad for decoder
}

// ---------- f32 -> bf16 conversion helpers ----------
__global__ void embed_kernel(const int* __restrict__ in1, const int* __restrict__ in2,
                             const float* __restrict__ emb, ushort_t* __restrict__ x0)
{
  int rowi = blockIdx.x;
  int l = threadIdx.x;    // 64 threads
  long r1 = (long)in1[rowi] * 400, r2 = (long)in2[rowi] * 400;
  ushort_t* d = x0 + (long)rowi * 800;
  for (int c = l; c < 800; c += 64)
    d[c] = f2b(c < 400 ? emb[r1 + c] : emb[r2 + c - 400]);
}

__global__ void pad_convert(const float* __restrict__ in, ushort_t* __restrict__ out,
                            int R, int Cin, int total, int Cp)
{
  int idx = blockIdx.x * 256 + threadIdx.x;
  if (idx >= total) return;
  int r = idx / Cp, c = idx - r * Cp;
  float v = (r < R && c < Cin) ? in[(long)r * Cin + c] : 0.f;
  out[idx] = f2b(v);
}

__global__ void init_state(const float* __restrict__ h_in,
                           ushort_t* __restrict__ hs, unsigned* __restrict__ flags)
{
  int idx = blockIdx.x * 256 + threadIdx.x;  // grid covers 64*1152 = 73728
  if (idx < 72 * 32) flags[idx] = 0u;        // reset producer flags for this layer
  if (idx < 64 * 1152) {
    int b = idx / 1152, c = idx - b * 1152;
    hs[idx] = (c < 1150) ? f2b(h_in[b * 1150 + c]) : (ushort_t)0;
  }
  if (idx < 100 * 128) {  // zero K-pad cols of hs rows 1..100
    int t = idx >> 7, r = idx & 127, b = r >> 1, k = r & 1;
    hs[(long)(t + 1) * 73728 + b * 1152 + 1150 + k] = 0;
  }
}

// =====================================================================
extern "C" void kernel_launch(void* const* d_in, const int* in_sizes, int n_in,
                              void* d_out, int out_size, void* d_ws, size_t ws_size,
                              hipStream_t stream) {
  (void)in_sizes; (void)n_in; (void)out_size; (void)ws_size;
  const int* input  = (const int*)d_in[0];
  const int* input2 = (const int*)d_in[1];
  const float* h_in[3] = {(const float*)d_in[2], (const float*)d_in[4], (const float*)d_in[6]};
  const float* c_in[3] = {(const float*)d_in[3], (const float*)d_in[5], (const float*)d_in[7]};
  const float* emb_W = (const float*)d_in[8];
  const float* W_ih[3] = {(const float*)d_in[9],  (const float*)d_in[13], (const float*)d_in[17]};
  const float* W_hh[3] = {(const float*)d_in[10], (const float*)d_in[14], (const float*)d_in[18]};
  const float* b_ih[3] = {(const float*)d_in[11], (const float*)d_in[15], (const float*)d_in[19]};
  const float* b_hh[3] = {(const float*)d_in[12], (const float*)d_in[16], (const float*)d_in[20]};
  const float* dec_W = (const float*)d_in[21];
  const float* dec_b = (const float*)d_in[22];
  float* out = (float*)d_out;

  // allow 144KB dynamic LDS for the persistent LSTM kernel
  hipFuncSetAttribute((const void*)lstm_layer,
                      hipFuncAttributeMaxDynamicSharedMemorySize, 147456);

  // ---- workspace: buffers alive during the final decoder GEMM + flags ----
  char* base = (char*)d_ws;
  size_t off = 0;
  auto walloc = [&](size_t bytes) { char* r = base + off; off += (bytes + 255) & ~(size_t)255; return r; };
  ushort_t* decWp = (ushort_t*)walloc(33280ull * 1152 * 2);   // 76,677,120
  ushort_t* attnB = (ushort_t*)walloc(6400ull * 1152 * 2);    // 14,745,600
  unsigned* flags = (unsigned*)walloc(72 * 128 + 256);

  // ---- layer-phase scratch inside d_out (852 MB f32; scratch uses first
  //      ~120 MB, all dead before the decoder GEMM which reads only ws). ----
  char* ob = (char*)d_out;
  ushort_t* G   = (ushort_t*)(ob + 0);            // 58,982,400
  ushort_t* x0  = (ushort_t*)(ob + 58982400);     // 10,240,000
  ushort_t* Wp  = (ushort_t*)(ob + 69222400);     // 10,616,832
  ushort_t* Whp = (ushort_t*)(ob + 79839232);     // 10,616,832
  ushort_t* hsA = (ushort_t*)(ob + 90456064);     // 14,893,056
  ushort_t* hsB = (ushort_t*)(ob + 105349120);    // -> end 120,242,176

  embed_kernel<<<6400, 64, 0, stream>>>(input, input2, emb_W, x0);

  ushort_t* hcur[3] = {hsA, hsB, hsA};
  const ushort_t* X = x0;
  int lda = 800, Kp = 800;
  for (int lyr = 0; lyr < 3; lyr++) {
    if (lyr == 0) {
      int tot = 4608 * 800;
      pad_convert<<<(tot + 255) / 256, 256, 0, stream>>>(W_ih[0], Wp, 4600, 800, tot, 800);
    } else {
      int tot = 4608 * 1152;
      pad_convert<<<(tot + 255) / 256, 256, 0, stream>>>(W_ih[lyr], Wp, 4600, 1150, tot, 1152);
    }
    {
      int tot = 4608 * 1152;
      pad_convert<<<(tot + 255) / 256, 256, 0, stream>>>(W_hh[lyr], Whp, 4600, 1150, tot, 1152);
    }
    gemm_bt<false><<<dim3(50, 36), 256, 0, stream>>>(X, Wp, (void*)G, b_ih[lyr], b_hh[lyr],
                                                     lda, Kp, 4608, Kp, 4600);
    init_state<<<288, 256, 0, stream>>>(h_in[lyr], hcur[lyr], flags);
    lstm_layer<<<72, 256, 147456, stream>>>(hcur[lyr], G, Whp, c_in[lyr], flags);
    X = hcur[lyr] + 73728;
    lda = 1152; Kp = 1152;
  }

  attn_kernel<<<6400, 256, 0, stream>>>(hsA + 73728, attnB);

  {
    int tot = 33280 * 1152;
    pad_convert<<<(tot + 255) / 256, 256, 0, stream>>>(dec_W, decWp, 33278, 1150, tot, 1152);
  }

  gemm_bt<true><<<dim3(50, 260), 256, 0, stream>>>(attnB, decWp, (void*)out, dec_b, nullptr,
                                                   1152, 1152, 33278, 1152, 33278);
}

// Round 10
// 3996.678 us; speedup vs baseline: 1.3039x; 1.3039x over previous
//
#include <hip/hip_runtime.h>
#include <stdint.h>

typedef unsigned short ushort_t;
typedef __bf16 bf16x8 __attribute__((ext_vector_type(8)));
typedef float f32x4 __attribute__((ext_vector_type(4)));

// ---------- bf16 <-> f32 (bit ops) ----------
__device__ __forceinline__ float b2f(ushort_t u) {
  union { unsigned u; float f; } v; v.u = ((unsigned)u) << 16; return v.f;
}
__device__ __forceinline__ ushort_t f2b(float f) {
  union { float f; unsigned u; } v; v.f = f;
  unsigned r = (v.u + 0x7FFFu + ((v.u >> 16) & 1u)) >> 16;
  return (ushort_t)r;
}

// ---------- fast transcendentals (HW v_exp_f32 based) ----------
__device__ __forceinline__ float sigm(float x)     { return 1.f / (1.f + __expf(-x)); }
__device__ __forceinline__ float tanhfast(float x) { return 1.f - 2.f / (1.f + __expf(2.f * x)); }

// ---------- device-coherent write-through stores (visible at MALL) ----------
__device__ __forceinline__ void store_short_wt(ushort_t* p, ushort_t v) {
  asm volatile("global_store_short %0, %1, off sc0 sc1"
               :: "v"(p), "v"((unsigned)v) : "memory");
}
__device__ __forceinline__ void store_uint_wt(unsigned* p, unsigned v) {
  asm volatile("global_store_dword %0, %1, off sc0 sc1"
               :: "v"(p), "v"(v) : "memory");
}

// ---------- global -> LDS direct load, 16B per lane ----------
__device__ __forceinline__ void gload_lds16(const void* g, void* lds) {
  auto l3 = reinterpret_cast<__attribute__((address_space(3))) unsigned*>(
      reinterpret_cast<uintptr_t>(lds));
  __builtin_amdgcn_global_load_lds(reinterpret_cast<const unsigned*>(g), l3, 16, 0, 0);
}

// =====================================================================
// GEMM: C[M,N] = A[M,K] @ B[N,K]^T + bias0 + bias1 (bf16 in, f32 acc,
// bf16 or f32 out). BM=BN=128, BK=32, 256 thr (4 waves), global_load_lds
// staging + bijective XCD swizzle when nwg%8==0.
// =====================================================================
template <bool F32OUT>
__global__ __launch_bounds__(256) void gemm_bt(
    const ushort_t* __restrict__ A, const ushort_t* __restrict__ B,
    void* __restrict__ Cv,
    const float* __restrict__ bias0, const float* __restrict__ bias1,
    int lda, int ldb, int ldc, int Kpad, int N)
{
  __shared__ alignas(16) ushort_t As[128 * 32];
  __shared__ alignas(16) ushort_t Bs[128 * 32];
  const int tid = threadIdx.x;
  const int w = tid >> 6, l = tid & 63;
  const int wr = w >> 1, wc = w & 1;

  unsigned nwg = gridDim.x * gridDim.y;
  unsigned wg = blockIdx.y * gridDim.x + blockIdx.x;
  if ((nwg & 7u) == 0u) {
    unsigned cpx = nwg >> 3;
    wg = (wg & 7u) * cpx + (wg >> 3);
  }
  const long m0 = (long)(wg % gridDim.x) * 128;
  const long n0 = (long)(wg / gridDim.x) * 128;

  const int lrow = l & 15, lk = (l >> 4) * 8;

  f32x4 acc[4][4] = {};

  const int c0 = tid, c1 = tid + 256;
  const int r0 = c0 >> 2, g0 = (c0 & 3) * 8;
  const int r1 = c1 >> 2, g1 = (c1 & 3) * 8;

  for (int k0 = 0; k0 < Kpad; k0 += 32) {
    gload_lds16(A + (m0 + r0) * lda + k0 + g0, As + c0 * 8);
    gload_lds16(A + (m0 + r1) * lda + k0 + g1, As + c1 * 8);
    gload_lds16(B + (n0 + r0) * ldb + k0 + g0, Bs + c0 * 8);
    gload_lds16(B + (n0 + r1) * ldb + k0 + g1, Bs + c1 * 8);
    __syncthreads();

    bf16x8 af[4], bfr[4];
#pragma unroll
    for (int mi = 0; mi < 4; mi++)
      af[mi] = *(const bf16x8*)(As + (wr * 64 + mi * 16 + lrow) * 32 + lk);
#pragma unroll
    for (int ni = 0; ni < 4; ni++)
      bfr[ni] = *(const bf16x8*)(Bs + (wc * 64 + ni * 16 + lrow) * 32 + lk);
#pragma unroll
    for (int mi = 0; mi < 4; mi++)
#pragma unroll
      for (int ni = 0; ni < 4; ni++)
        acc[mi][ni] = __builtin_amdgcn_mfma_f32_16x16x32_bf16(af[mi], bfr[ni], acc[mi][ni], 0, 0, 0);
    __syncthreads();
  }

  const int rbase = (l >> 4) * 4;
#pragma unroll
  for (int ni = 0; ni < 4; ni++) {
    int gcol = (int)n0 + wc * 64 + ni * 16 + lrow;
    if (gcol < N) {
      float badd = 0.f;
      if (bias0) badd += bias0[gcol];
      if (bias1) badd += bias1[gcol];
#pragma unroll
      for (int mi = 0; mi < 4; mi++) {
#pragma unroll
        for (int r = 0; r < 4; r++) {
          long grow = m0 + wr * 64 + mi * 16 + rbase + r;
          float v = acc[mi][ni][r] + badd;
          if (F32OUT) ((float*)Cv)[grow * ldc + gcol] = v;
          else        ((ushort_t*)Cv)[grow * ldc + gcol] = f2b(v);
        }
      }
    }
  }
}

// =====================================================================
// Persistent LSTM layer: per-slice flags, LOW-TRAFFIC polling.
// 72 blocks (16-unit slices) x 256 thr (4 waves = 4 batch-16 tiles).
// Wave 0 takes ONE snapshot of the 72 flags per step (lane l -> slice l,
// 8 lanes double-cover 64..71), then targeted re-polls ONLY pending lanes
// with s_sleep(8) backoff; own slice exempt. Other waves wait at a block
// sync. Chunk consumption order rotated by block (start = us>>1) to
// spread h-load traffic. Whh slice in 144KB LDS; cell in regs; h via
// write-through stores; per-wave vmcnt drain + sync + one flag store.
// =====================================================================
__global__ __launch_bounds__(256) void lstm_layer(
    ushort_t* __restrict__ hs,        // [101][64][1152] bf16
    const ushort_t* __restrict__ G,   // [6400][4608] bf16 (x@Wih^T + biases)
    const ushort_t* __restrict__ Whh, // padded [4608][1152] bf16
    const float* __restrict__ c_in,   // [64][1150] f32 initial cell
    unsigned* __restrict__ flags)     // 72 lines of 128B, zeroed per layer
{
  extern __shared__ ushort_t Bsh[];   // 4*16*144 chunks of 16B = 147456 B
  const int tid = threadIdx.x;
  const int w = tid >> 6, l = tid & 63;
  const int us = blockIdx.x;              // unit slice [0,72)
  const int lrow = l & 15, hi = l >> 4, lk = hi * 8;
  const int u = us * 16 + lrow;
  const int usafe = (u < 1150) ? u : 0;
  const int row0 = w * 16 + hi * 4;       // first batch row of this lane's D regs
  const int x7 = lrow & 7;
  const int start = us >> 1;              // rotated chunk start

  // ---- stage Whh slice into LDS (once), chunk-swizzled: phys = c ^ (row&7) ----
  for (int ci = tid; ci < 9216; ci += 256) {
    int gate = ci / 2304;
    int rem  = ci - gate * 2304;
    int row  = rem / 144;
    int c    = rem - row * 144;
    bf16x8 v = *(const bf16x8*)(Whh + ((long)(gate * 1150 + us * 16 + row)) * 1152 + c * 8);
    *(bf16x8*)(Bsh + (((gate * 16 + row) * 144) + (c ^ (row & 7))) * 8) = v;
  }
  const ushort_t* Bg0 = Bsh + ((0 * 16 + lrow) * 144) * 8;
  const ushort_t* Bg1 = Bsh + ((1 * 16 + lrow) * 144) * 8;
  const ushort_t* Bg2 = Bsh + ((2 * 16 + lrow) * 144) * 8;
  const ushort_t* Bg3 = Bsh + ((3 * 16 + lrow) * 144) * 8;

  // ---- cell state in registers (lane owns rows row0..row0+3, col u) ----
  f32x4 cc = {};
  if (u < 1150) {
#pragma unroll
    for (int r = 0; r < 4; ++r) cc[r] = c_in[(row0 + r) * 1150 + u];
  }
  __syncthreads();   // LDS staging visible

  const int s1 = l, s2 = 64 + (l & 7);    // slices this lane watches (wave 0)

  for (int t = 0; t < 100; ++t) {
    // G prefetch for this step (independent of flags; in flight during wait)
    ushort_t gvv[16];
    {
      const ushort_t* gp = G + ((long)t * 64 + row0) * 4608 + usafe;
#pragma unroll
      for (int r = 0; r < 4; ++r)
#pragma unroll
        for (int g = 0; g < 4; ++g)
          gvv[r * 4 + g] = gp[(long)r * 4608 + g * 1150];
    }

    if (t > 0) {
      if (w == 0) {
        const unsigned tt = (unsigned)t;
        unsigned f1 = (s1 == us) ? tt :
            __hip_atomic_load(flags + (s1 << 5), __ATOMIC_RELAXED, __HIP_MEMORY_SCOPE_AGENT);
        unsigned f2 = (s2 == us) ? tt :
            __hip_atomic_load(flags + (s2 << 5), __ATOMIC_RELAXED, __HIP_MEMORY_SCOPE_AGENT);
        unsigned long long p1 = __ballot(f1 >= tt);
        unsigned long long p2 = __ballot(f2 >= tt);
        while ((p1 & p2) != ~0ull) {
          __builtin_amdgcn_s_sleep(8);   // 512-cycle backoff: keep MALL clear
          if (!((p1 >> l) & 1))
            f1 = __hip_atomic_load(flags + (s1 << 5), __ATOMIC_RELAXED, __HIP_MEMORY_SCOPE_AGENT);
          if (!((p2 >> l) & 1))
            f2 = __hip_atomic_load(flags + (s2 << 5), __ATOMIC_RELAXED, __HIP_MEMORY_SCOPE_AGENT);
          p1 = __ballot(f1 >= tt);
          p2 = __ballot(f2 >= tt);
        }
      }
      __syncthreads();                   // release waves 1..3
      asm volatile("" ::: "memory");     // no h-load hoisting above the gate
    }

    const ushort_t* hp = hs + (long)t * 73728 + (long)(w * 16 + lrow) * 1152 + lk;
    f32x4 a0 = {}, a1 = {}, a2 = {}, a3 = {};
#pragma unroll 4
    for (int i = 0; i < 36; ++i) {
      int kc = start + i; if (kc >= 36) kc -= 36;
      bf16x8 a = *(const bf16x8*)(hp + kc * 32);
      int pc8 = ((kc * 4 + hi) ^ x7) * 8;
      a0 = __builtin_amdgcn_mfma_f32_16x16x32_bf16(a, *(const bf16x8*)(Bg0 + pc8), a0, 0, 0, 0);
      a1 = __builtin_amdgcn_mfma_f32_16x16x32_bf16(a, *(const bf16x8*)(Bg1 + pc8), a1, 0, 0, 0);
      a2 = __builtin_amdgcn_mfma_f32_16x16x32_bf16(a, *(const bf16x8*)(Bg2 + pc8), a2, 0, 0, 0);
      a3 = __builtin_amdgcn_mfma_f32_16x16x32_bf16(a, *(const bf16x8*)(Bg3 + pc8), a3, 0, 0, 0);
    }

    if (u < 1150) {
#pragma unroll
      for (int r = 0; r < 4; ++r) {
        float iv = a0[r] + b2f(gvv[r * 4 + 0]);
        float fv = a1[r] + b2f(gvv[r * 4 + 1]);
        float gg = a2[r] + b2f(gvv[r * 4 + 2]);
        float ov = a3[r] + b2f(gvv[r * 4 + 3]);
        float cn = sigm(fv) * cc[r] + sigm(iv) * tanhfast(gg);
        cc[r] = cn;
        float hv = sigm(ov) * tanhfast(cn);
        store_short_wt(hs + (long)(t + 1) * 73728 + (long)(row0 + r) * 1152 + u, f2b(hv));
      }
    }

    if (t != 99) {
      asm volatile("s_waitcnt vmcnt(0)" ::: "memory");  // per-wave h-store drain
      __syncthreads();                                  // all 4 waves drained
      if (tid == 0) store_uint_wt(flags + (us << 5), (unsigned)(t + 1));
    }
  }
}

// =====================================================================
// Fused causal attention for one (t,b): scores -> softmax -> PV. f32 math.
// =====================================================================
__global__ __launch_bounds__(256) void attn_kernel(
    const ushort_t* __restrict__ hs2,  // base at hs[1]: [100][64][1152] bf16
    ushort_t* __restrict__ outp)       // [6400][1152] bf16
{
  __shared__ float qf[1152];
  __shared__ float sc[104];
  __shared__ float sinv;
  const int rowi = blockIdx.x;  // t*64 + b
  const int t = rowi >> 6, b = rowi & 63;
  const int tid = threadIdx.x;
  const int w = tid >> 6, l = tid & 63;

  const ushort_t* q = hs2 + (long)rowi * 1152;
  for (int c = tid; c < 1150; c += 256) qf[c] = b2f(q[c]);
  __syncthreads();

  for (int s = w; s <= t; s += 4) {
    const ushort_t* k = hs2 + (long)(s * 64 + b) * 1152;
    float p = 0.f;
    for (int h = l; h < 1150; h += 64) p += qf[h] * b2f(k[h]);
    for (int off = 32; off; off >>= 1) p += __shfl_down(p, off);
    if (l == 0) sc[s] = p;
  }
  __syncthreads();

  if (w == 0) {
    float m = -1e30f;
    for (int s = l; s <= t; s += 64) m = fmaxf(m, sc[s]);
    for (int off = 32; off; off >>= 1) m = fmaxf(m, __shfl_down(m, off));
    m = __shfl(m, 0);
    float sum = 0.f;
    for (int s = l; s <= t; s += 64) { float e = __expf(sc[s] - m); sc[s] = e; sum += e; }
    for (int off = 32; off; off >>= 1) sum += __shfl_down(sum, off);
    if (l == 0) sinv = 1.f / sum;
  }
  __syncthreads();

  const float si = sinv;
  for (int h = tid; h < 1150; h += 256) {
    float a = 0.f;
    for (int s = 0; s <= t; s++) a += sc[s] * b2f(hs2[(long)(s * 64 + b) * 1152 + h]);
    outp[(long)rowi * 1152 + h] = f2b(a * si);
  }
  if (tid < 2) outp[(long)rowi * 1152 + 1150 + tid] = 0;  // zero K-pad for decoder
}

// ---------- f32 -> bf16 conversion helpers ----------
__global__ void embed_kernel(const int* __restrict__ in1, const int* __restrict__ in2,
                             const float* __restrict__ emb, ushort_t* __restrict__ x0)
{
  int rowi = blockIdx.x;
  int l = threadIdx.x;    // 64 threads
  long r1 = (long)in1[rowi] * 400, r2 = (long)in2[rowi] * 400;
  ushort_t* d = x0 + (long)rowi * 800;
  for (int c = l; c < 800; c += 64)
    d[c] = f2b(c < 400 ? emb[r1 + c] : emb[r2 + c - 400]);
}

__global__ void pad_convert(const float* __restrict__ in, ushort_t* __restrict__ out,
                            int R, int Cin, int total, int Cp)
{
  int idx = blockIdx.x * 256 + threadIdx.x;
  if (idx >= total) return;
  int r = idx / Cp, c = idx - r * Cp;
  float v = (r < R && c < Cin) ? in[(long)r * Cin + c] : 0.f;
  out[idx] = f2b(v);
}

__global__ void init_state(const float* __restrict__ h_in,
                           ushort_t* __restrict__ hs, unsigned* __restrict__ flags)
{
  int idx = blockIdx.x * 256 + threadIdx.x;  // grid covers 64*1152 = 73728
  if (idx < 72 * 32) flags[idx] = 0u;        // reset producer flags for this layer
  if (idx < 64 * 1152) {
    int b = idx / 1152, c = idx - b * 1152;
    hs[idx] = (c < 1150) ? f2b(h_in[b * 1150 + c]) : (ushort_t)0;
  }
  if (idx < 100 * 128) {  // zero K-pad cols of hs rows 1..100
    int t = idx >> 7, r = idx & 127, b = r >> 1, k = r & 1;
    hs[(long)(t + 1) * 73728 + b * 1152 + 1150 + k] = 0;
  }
}

// =====================================================================
extern "C" void kernel_launch(void* const* d_in, const int* in_sizes, int n_in,
                              void* d_out, int out_size, void* d_ws, size_t ws_size,
                              hipStream_t stream) {
  (void)in_sizes; (void)n_in; (void)out_size; (void)ws_size;
  const int* input  = (const int*)d_in[0];
  const int* input2 = (const int*)d_in[1];
  const float* h_in[3] = {(const float*)d_in[2], (const float*)d_in[4], (const float*)d_in[6]};
  const float* c_in[3] = {(const float*)d_in[3], (const float*)d_in[5], (const float*)d_in[7]};
  const float* emb_W = (const float*)d_in[8];
  const float* W_ih[3] = {(const float*)d_in[9],  (const float*)d_in[13], (const float*)d_in[17]};
  const float* W_hh[3] = {(const float*)d_in[10], (const float*)d_in[14], (const float*)d_in[18]};
  const float* b_ih[3] = {(const float*)d_in[11], (const float*)d_in[15], (const float*)d_in[19]};
  const float* b_hh[3] = {(const float*)d_in[12], (const float*)d_in[16], (const float*)d_in[20]};
  const float* dec_W = (const float*)d_in[21];
  const float* dec_b = (const float*)d_in[22];
  float* out = (float*)d_out;

  // allow 144KB dynamic LDS for the persistent LSTM kernel
  hipFuncSetAttribute((const void*)lstm_layer,
                      hipFuncAttributeMaxDynamicSharedMemorySize, 147456);

  // ---- workspace: buffers alive during the final decoder GEMM + flags ----
  char* base = (char*)d_ws;
  size_t off = 0;
  auto walloc = [&](size_t bytes) { char* r = base + off; off += (bytes + 255) & ~(size_t)255; return r; };
  ushort_t* decWp = (ushort_t*)walloc(33280ull * 1152 * 2);   // 76,677,120
  ushort_t* attnB = (ushort_t*)walloc(6400ull * 1152 * 2);    // 14,745,600
  unsigned* flags = (unsigned*)walloc(72 * 128 + 256);

  // ---- layer-phase scratch inside d_out (852 MB f32; scratch uses first
  //      ~120 MB, all dead before the decoder GEMM which reads only ws). ----
  char* ob = (char*)d_out;
  ushort_t* G   = (ushort_t*)(ob + 0);            // 58,982,400
  ushort_t* x0  = (ushort_t*)(ob + 58982400);     // 10,240,000
  ushort_t* Wp  = (ushort_t*)(ob + 69222400);     // 10,616,832
  ushort_t* Whp = (ushort_t*)(ob + 79839232);     // 10,616,832
  ushort_t* hsA = (ushort_t*)(ob + 90456064);     // 14,893,056
  ushort_t* hsB = (ushort_t*)(ob + 105349120);    // -> end 120,242,176

  embed_kernel<<<6400, 64, 0, stream>>>(input, input2, emb_W, x0);

  ushort_t* hcur[3] = {hsA, hsB, hsA};
  const ushort_t* X = x0;
  int lda = 800, Kp = 800;
  for (int lyr = 0; lyr < 3; lyr++) {
    if (lyr == 0) {
      int tot = 4608 * 800;
      pad_convert<<<(tot + 255) / 256, 256, 0, stream>>>(W_ih[0], Wp, 4600, 800, tot, 800);
    } else {
      int tot = 4608 * 1152;
      pad_convert<<<(tot + 255) / 256, 256, 0, stream>>>(W_ih[lyr], Wp, 4600, 1150, tot, 1152);
    }
    {
      int tot = 4608 * 1152;
      pad_convert<<<(tot + 255) / 256, 256, 0, stream>>>(W_hh[lyr], Whp, 4600, 1150, tot, 1152);
    }
    gemm_bt<false><<<dim3(50, 36), 256, 0, stream>>>(X, Wp, (void*)G, b_ih[lyr], b_hh[lyr],
                                                     lda, Kp, 4608, Kp, 4600);
    init_state<<<288, 256, 0, stream>>>(h_in[lyr], hcur[lyr], flags);
    lstm_layer<<<72, 256, 147456, stream>>>(hcur[lyr], G, Whp, c_in[lyr], flags);
    X = hcur[lyr] + 73728;
    lda = 1152; Kp = 1152;
  }

  attn_kernel<<<6400, 256, 0, stream>>>(hsA + 73728, attnB);

  {
    int tot = 33280 * 1152;
    pad_convert<<<(tot + 255) / 256, 256, 0, stream>>>(dec_W, decWp, 33278, 1150, tot, 1152);
  }

  gemm_bt<true><<<dim3(50, 260), 256, 0, stream>>>(attnB, decWp, (void*)out, dec_b, nullptr,
                                                   1152, 1152, 33278, 1152, 33278);
}